// Round 1
// baseline (22015.076 us; speedup 1.0000x reference)
//
#include <hip/hip_runtime.h>
#include <math.h>

namespace {
constexpr int BATCH = 32;
constexpr int S = 197;
constexpr int D = 768;
constexpr int NH = 12;
constexpr int DH = 64;
constexpr int MLPD = 3072;
constexpr int LYR = 12;
constexpr int NOUT = 1000;
constexpr int NPATCH = 196;
constexpr int T = BATCH * S;        // 6304
constexpr int TP = BATCH * NPATCH;  // 6272
constexpr int QT = 32;              // attention q-tile rows
}

// ---------------- patchify: images[b,c,224,224] -> patches[b*196, 768] ----------------
__global__ void patchify_kernel(const float* __restrict__ img, float* __restrict__ patches) {
  int idx = blockIdx.x * 256 + threadIdx.x;
  if (idx >= TP * 768) return;
  int t = idx / 768, kf = idx - t * 768;
  int b = t / NPATCH, p = t - b * NPATCH;
  int pi = p / 14, pj = p - pi * 14;
  int c = kf >> 8, rr = (kf >> 4) & 15, cc = kf & 15;
  patches[idx] = img[((size_t)(b * 3 + c) * 224 + pi * 16 + rr) * 224 + pj * 16 + cc];
}

// ---------------- generic tiled f32 GEMM: C = [gelu](A@B + bias) [+C] ----------------
// A[M,K] row-major, B[K,N] row-major. BM=BN=128, BK=16, 256 thr, 8x8 micro-tile.
template<bool GELU, bool ACCUM>
__global__ __launch_bounds__(256) void gemm128_kernel(
    const float* __restrict__ A, const float* __restrict__ Bm,
    const float* __restrict__ bias, float* __restrict__ Cm,
    int M, int N, int K) {
  __shared__ __align__(16) float As[16][128];
  __shared__ __align__(16) float Bs[16][128];
  const int tid = threadIdx.x;
  const int tx = tid & 15, ty = tid >> 4;
  const int m0 = blockIdx.y * 128, n0 = blockIdx.x * 128;
  const int ar = tid >> 2, akq = tid & 3;    // A: row within half-tile, k-quad
  const int bkr = tid >> 5, bnq = tid & 31;  // B: k-row, n-quad

  float acc[2][2][4][4];
  #pragma unroll
  for (int a = 0; a < 2; ++a)
    #pragma unroll
    for (int b = 0; b < 2; ++b)
      #pragma unroll
      for (int i = 0; i < 4; ++i)
        #pragma unroll
        for (int j = 0; j < 4; ++j) acc[a][b][i][j] = 0.f;

  const bool r0ok = (m0 + ar) < M, r1ok = (m0 + 64 + ar) < M;
  const float* Ap0 = A + (size_t)(m0 + ar) * K + akq * 4;
  const float* Ap1 = A + (size_t)(m0 + 64 + ar) * K + akq * 4;
  const float* Bp0 = Bm + (size_t)bkr * N + n0 + bnq * 4;
  const float* Bp1 = Bm + (size_t)(bkr + 8) * N + n0 + bnq * 4;

  for (int kt = 0; kt < K; kt += 16) {
    float4 a0 = r0ok ? *(const float4*)(Ap0 + kt) : make_float4(0.f, 0.f, 0.f, 0.f);
    float4 a1 = r1ok ? *(const float4*)(Ap1 + kt) : make_float4(0.f, 0.f, 0.f, 0.f);
    float4 b0 = *(const float4*)(Bp0 + (size_t)kt * N);
    float4 b1 = *(const float4*)(Bp1 + (size_t)kt * N);
    __syncthreads();
    As[akq * 4 + 0][ar] = a0.x; As[akq * 4 + 1][ar] = a0.y;
    As[akq * 4 + 2][ar] = a0.z; As[akq * 4 + 3][ar] = a0.w;
    As[akq * 4 + 0][64 + ar] = a1.x; As[akq * 4 + 1][64 + ar] = a1.y;
    As[akq * 4 + 2][64 + ar] = a1.z; As[akq * 4 + 3][64 + ar] = a1.w;
    *(float4*)&Bs[bkr][bnq * 4] = b0;
    *(float4*)&Bs[bkr + 8][bnq * 4] = b1;
    __syncthreads();
    #pragma unroll
    for (int kk = 0; kk < 16; ++kk) {
      float4 t0 = *(const float4*)&As[kk][ty * 4];
      float4 t1 = *(const float4*)&As[kk][64 + ty * 4];
      float4 t2 = *(const float4*)&Bs[kk][tx * 4];
      float4 t3 = *(const float4*)&Bs[kk][64 + tx * 4];
      float am0[4] = {t0.x, t0.y, t0.z, t0.w};
      float am1[4] = {t1.x, t1.y, t1.z, t1.w};
      float bn0[4] = {t2.x, t2.y, t2.z, t2.w};
      float bn1[4] = {t3.x, t3.y, t3.z, t3.w};
      #pragma unroll
      for (int mi = 0; mi < 4; ++mi)
        #pragma unroll
        for (int ni = 0; ni < 4; ++ni) {
          acc[0][0][mi][ni] += am0[mi] * bn0[ni];
          acc[0][1][mi][ni] += am0[mi] * bn1[ni];
          acc[1][0][mi][ni] += am1[mi] * bn0[ni];
          acc[1][1][mi][ni] += am1[mi] * bn1[ni];
        }
    }
  }

  #pragma unroll
  for (int mh = 0; mh < 2; ++mh)
    #pragma unroll
    for (int mi = 0; mi < 4; ++mi) {
      int row = m0 + mh * 64 + ty * 4 + mi;
      if (row >= M) continue;
      #pragma unroll
      for (int nh = 0; nh < 2; ++nh) {
        int col = n0 + nh * 64 + tx * 4;
        float4 r;
        r.x = acc[mh][nh][mi][0] + bias[col + 0];
        r.y = acc[mh][nh][mi][1] + bias[col + 1];
        r.z = acc[mh][nh][mi][2] + bias[col + 2];
        r.w = acc[mh][nh][mi][3] + bias[col + 3];
        if (GELU) {
          r.x = 0.5f * r.x * (1.f + erff(r.x * 0.70710678118654752f));
          r.y = 0.5f * r.y * (1.f + erff(r.y * 0.70710678118654752f));
          r.z = 0.5f * r.z * (1.f + erff(r.z * 0.70710678118654752f));
          r.w = 0.5f * r.w * (1.f + erff(r.w * 0.70710678118654752f));
        }
        float* cp = Cm + (size_t)row * N + col;
        if (ACCUM) {
          float4 old = *(const float4*)cp;
          r.x += old.x; r.y += old.y; r.z += old.z; r.w += old.w;
        }
        *(float4*)cp = r;
      }
    }
}

// ---------------- x = concat(cls, tokens) + pos ----------------
__global__ void build_x_kernel(const float* __restrict__ tokens,
                               const float* __restrict__ cls,
                               float* __restrict__ x) {
  int idx = blockIdx.x * 256 + threadIdx.x;
  if (idx >= BATCH * S * D) return;
  int d = idx % D;
  int bs = idx / D;
  int s = bs % S;
  int b = bs / S;
  double p = exp((double)d * (-9.210340371976184 / 768.0));  // 10000^(-d/768)
  double ang = (double)s * p;
  float pe = (d & 1) ? (float)cos(ang) : (float)sin(ang);
  float val = (s == 0) ? cls[d] : tokens[((size_t)b * NPATCH + (s - 1)) * D + d];
  x[idx] = val + pe;
}

// ---------------- LayerNorm: out = (x-m)/sqrt(var+eps)*g + b, one block/token ----------------
__global__ __launch_bounds__(192) void layernorm_kernel(
    const float* __restrict__ x, const float* __restrict__ g,
    const float* __restrict__ b, float* __restrict__ out) {
  int t = blockIdx.x;
  int tid = threadIdx.x;
  const float4* xr = (const float4*)(x + (size_t)t * D);
  float4 v = xr[tid];
  float s = v.x + v.y + v.z + v.w;
  float s2 = v.x * v.x + v.y * v.y + v.z * v.z + v.w * v.w;
  #pragma unroll
  for (int off = 32; off; off >>= 1) {
    s += __shfl_xor(s, off);
    s2 += __shfl_xor(s2, off);
  }
  __shared__ float rs[3], rs2[3];
  int wid = tid >> 6;
  if ((tid & 63) == 0) { rs[wid] = s; rs2[wid] = s2; }
  __syncthreads();
  float tot = rs[0] + rs[1] + rs[2];
  float tot2 = rs2[0] + rs2[1] + rs2[2];
  float mean = tot * (1.f / D);
  float var = tot2 * (1.f / D) - mean * mean;
  float rstd = rsqrtf(var + 1e-5f);
  float4 gv = ((const float4*)g)[tid];
  float4 bv = ((const float4*)b)[tid];
  float4 o;
  o.x = (v.x - mean) * rstd * gv.x + bv.x;
  o.y = (v.y - mean) * rstd * gv.y + bv.y;
  o.z = (v.z - mean) * rstd * gv.z + bv.z;
  o.w = (v.w - mean) * rstd * gv.w + bv.w;
  ((float4*)(out + (size_t)t * D))[tid] = o;
}

// ---------------- per-(b,head) QKV projection (block-diagonal 64x64) ----------------
// dyn LDS: wq[4096] wk[4096] wv[4096] hs[197*64]  (99,584 B)
__global__ __launch_bounds__(256) void qkv_kernel(
    const float* __restrict__ h, const float* __restrict__ Wq,
    const float* __restrict__ Wk, const float* __restrict__ Wv,
    const float* __restrict__ bq, const float* __restrict__ bk,
    const float* __restrict__ bv, float* __restrict__ q,
    float* __restrict__ k, float* __restrict__ v) {
  extern __shared__ float sm[];
  float* wqs = sm;
  float* wks = sm + 4096;
  float* wvs = sm + 8192;
  float* hs = sm + 12288;  // [197][64]
  int tid = threadIdx.x;
  int b = blockIdx.x, hh = blockIdx.y;
  const float4* wq4 = (const float4*)(Wq + (size_t)hh * 4096);
  const float4* wk4 = (const float4*)(Wk + (size_t)hh * 4096);
  const float4* wv4 = (const float4*)(Wv + (size_t)hh * 4096);
  for (int i = tid; i < 1024; i += 256) {
    ((float4*)wqs)[i] = wq4[i];
    ((float4*)wks)[i] = wk4[i];
    ((float4*)wvs)[i] = wv4[i];
  }
  for (int i = tid; i < S * 16; i += 256) {
    int s = i >> 4, e4 = i & 15;
    ((float4*)hs)[i] = *(const float4*)(h + (size_t)(b * S + s) * D + hh * DH + e4 * 4);
  }
  __syncthreads();
  for (int o = tid; o < S * 64; o += 256) {
    int s = o >> 6, e = o & 63;
    float aq = bq[hh * 64 + e], ak = bk[hh * 64 + e], av = bv[hh * 64 + e];
    #pragma unroll 16
    for (int d = 0; d < 64; ++d) {
      float hv = hs[s * 64 + d];
      aq += hv * wqs[d * 64 + e];
      ak += hv * wks[d * 64 + e];
      av += hv * wvs[d * 64 + e];
    }
    size_t oidx = ((size_t)(b * S + s) * NH + hh) * DH + e;
    q[oidx] = aq; k[oidx] = ak; v[oidx] = av;
  }
}

// ---------------- fused attention per (b, head, q-tile): x += softmax(qk^T/8) v ----------------
// dyn LDS layout (floats): vs[197*64] qs[32*64] sc[32*197] ks[197*65]  (135,060 B)
__global__ __launch_bounds__(256) void attn_kernel(
    const float* __restrict__ q, const float* __restrict__ k,
    const float* __restrict__ v, float* __restrict__ x) {
  extern __shared__ float sm[];
  float* vs = sm;                  // [197][64]
  float* qs = vs + 197 * 64;       // [32][64]
  float* sc = qs + 32 * 64;        // [32][197]
  float* ks = sc + 32 * 197;       // [197][65]  (pad 65 kills column bank conflict)
  int tid = threadIdx.x;
  int b = blockIdx.x, hh = blockIdx.y, qt = blockIdx.z;
  int q0 = qt * QT;
  int rows = min(QT, S - q0);

  for (int i = tid; i < S * 64; i += 256) {
    int s = i >> 6, e = i & 63;
    size_t src = ((size_t)(b * S + s) * NH + hh) * DH + e;
    ks[s * 65 + e] = k[src];
    vs[i] = v[src];
  }
  for (int i = tid; i < rows * 64; i += 256) {
    int r = i >> 6, e = i & 63;
    qs[i] = q[((size_t)(b * S + q0 + r) * NH + hh) * DH + e];
  }
  __syncthreads();

  // scores
  for (int o = tid; o < rows * S; o += 256) {
    int r = o / S, kj = o - r * S;
    float acc = 0.f;
    #pragma unroll 16
    for (int e = 0; e < 64; ++e) acc += qs[r * 64 + e] * ks[kj * 65 + e];
    sc[r * S + kj] = acc * 0.125f;
  }
  __syncthreads();

  // softmax: one wave per row
  int wid = tid >> 6, lane = tid & 63;
  for (int r = wid; r < rows; r += 4) {
    float vals[4];
    float mx = -1e30f;
    #pragma unroll
    for (int c = 0; c < 4; ++c) {
      int idx = c * 64 + lane;
      vals[c] = (idx < S) ? sc[r * S + idx] : -1e30f;
      mx = fmaxf(mx, vals[c]);
    }
    #pragma unroll
    for (int off = 32; off; off >>= 1) mx = fmaxf(mx, __shfl_xor(mx, off));
    float sum = 0.f;
    #pragma unroll
    for (int c = 0; c < 4; ++c) {
      int idx = c * 64 + lane;
      if (idx < S) { float e = expf(vals[c] - mx); sc[r * S + idx] = e; sum += e; }
    }
    #pragma unroll
    for (int off = 32; off; off >>= 1) sum += __shfl_xor(sum, off);
    float inv = 1.f / sum;
    #pragma unroll
    for (int c = 0; c < 4; ++c) {
      int idx = c * 64 + lane;
      if (idx < S) sc[r * S + idx] *= inv;
    }
  }
  __syncthreads();

  // PV, accumulate into residual stream
  for (int o = tid; o < rows * 64; o += 256) {
    int r = o >> 6, e = o & 63;
    float acc = 0.f;
    #pragma unroll 4
    for (int kj = 0; kj < S; ++kj) acc += sc[r * S + kj] * vs[kj * 64 + e];
    x[(size_t)(b * S + q0 + r) * D + hh * DH + e] += acc;
  }
}

// ---------------- classifier head: out[b,o] = x[b,0,:] @ Wo + bo ----------------
__global__ __launch_bounds__(256) void head_kernel(
    const float* __restrict__ x, const float* __restrict__ Wo,
    const float* __restrict__ bo, float* __restrict__ out) {
  __shared__ float xs[D];
  int b = blockIdx.x, tid = threadIdx.x;
  for (int i = tid; i < D / 4; i += 256)
    ((float4*)xs)[i] = ((const float4*)(x + (size_t)b * S * D))[i];
  __syncthreads();
  int o = blockIdx.y * 256 + tid;
  if (o < NOUT) {
    float acc = bo[o];
    #pragma unroll 8
    for (int d = 0; d < D; ++d) acc += xs[d] * Wo[(size_t)d * NOUT + o];
    out[(size_t)b * NOUT + o] = acc;
  }
}

extern "C" void kernel_launch(void* const* d_in, const int* in_sizes, int n_in,
                              void* d_out, int out_size, void* d_ws, size_t ws_size,
                              hipStream_t stream) {
  const float* images = (const float*)d_in[0];
  const float* W1 = (const float*)d_in[1];
  const float* b1 = (const float*)d_in[2];
  const float* cls = (const float*)d_in[3];
  const float* ln1_g = (const float*)d_in[4];
  const float* ln1_b = (const float*)d_in[5];
  const float* Wq = (const float*)d_in[6];
  const float* bq = (const float*)d_in[7];
  const float* Wk = (const float*)d_in[8];
  const float* bk = (const float*)d_in[9];
  const float* Wv = (const float*)d_in[10];
  const float* bv = (const float*)d_in[11];
  const float* ln2_g = (const float*)d_in[12];
  const float* ln2_b = (const float*)d_in[13];
  const float* Wm1 = (const float*)d_in[14];
  const float* bm1 = (const float*)d_in[15];
  const float* Wm2 = (const float*)d_in[16];
  const float* bm2 = (const float*)d_in[17];
  const float* Wo = (const float*)d_in[18];
  const float* bo = (const float*)d_in[19];
  float* out = (float*)d_out;

  const size_t TD = (size_t)T * D;
  float* x = (float*)d_ws;
  float* h = x + TD;
  float* q = h + TD;
  float* kbuf = q + TD;
  float* vbuf = kbuf + TD;
  float* mlp = vbuf + TD;  // [T, 3072]; also aliases patches [TP, 768]

  const size_t qkv_lds = (size_t)(3 * 4096 + S * 64) * sizeof(float);
  const size_t attn_lds = (size_t)(197 * 65 + 197 * 64 + 32 * 64 + 32 * 197) * sizeof(float);
  hipFuncSetAttribute((const void*)qkv_kernel,
                      hipFuncAttributeMaxDynamicSharedMemorySize, (int)qkv_lds);
  hipFuncSetAttribute((const void*)attn_kernel,
                      hipFuncAttributeMaxDynamicSharedMemorySize, (int)attn_lds);

  // patch embedding
  patchify_kernel<<<(TP * 768 + 255) / 256, 256, 0, stream>>>(images, mlp);
  gemm128_kernel<false, false><<<dim3(D / 128, (TP + 127) / 128), 256, 0, stream>>>(
      mlp, W1, b1, h, TP, D, 768);
  build_x_kernel<<<(BATCH * S * D + 255) / 256, 256, 0, stream>>>(h, cls, x);

  for (int l = 0; l < LYR; ++l) {
    layernorm_kernel<<<T, 192, 0, stream>>>(x, ln1_g + (size_t)l * D, ln1_b + (size_t)l * D, h);
    qkv_kernel<<<dim3(BATCH, NH), 256, qkv_lds, stream>>>(
        h, Wq + (size_t)l * NH * DH * DH, Wk + (size_t)l * NH * DH * DH,
        Wv + (size_t)l * NH * DH * DH, bq + (size_t)l * NH * DH,
        bk + (size_t)l * NH * DH, bv + (size_t)l * NH * DH, q, kbuf, vbuf);
    attn_kernel<<<dim3(BATCH, NH, (S + QT - 1) / QT), 256, attn_lds, stream>>>(
        q, kbuf, vbuf, x);
    layernorm_kernel<<<T, 192, 0, stream>>>(x, ln2_g + (size_t)l * D, ln2_b + (size_t)l * D, h);
    gemm128_kernel<true, false><<<dim3(MLPD / 128, (T + 127) / 128), 256, 0, stream>>>(
        h, Wm1 + (size_t)l * D * MLPD, bm1 + (size_t)l * MLPD, mlp, T, MLPD, D);
    gemm128_kernel<false, true><<<dim3(D / 128, (T + 127) / 128), 256, 0, stream>>>(
        mlp, Wm2 + (size_t)l * MLPD * D, bm2 + (size_t)l * D, x, T, D, MLPD);
  }

  head_kernel<<<dim3(BATCH, (NOUT + 255) / 256), 256, 0, stream>>>(x, Wo, bo, out);
}

// Round 3
// 5922.172 us; speedup vs baseline: 3.7174x; 3.7174x over previous
//
#include <hip/hip_runtime.h>
#include <math.h>

namespace {
constexpr int BATCH = 32;
constexpr int S = 197;
constexpr int D = 768;
constexpr int NH = 12;
constexpr int MLPD = 3072;
constexpr int LYR = 12;
constexpr int NOUT = 1000;
constexpr int NPATCH = 196;
constexpr int T = BATCH * S;        // 6304
constexpr int TP = BATCH * NPATCH;  // 6272
constexpr int TPAD = 6400;          // 50*128
constexpr int QT2 = 30;             // attn q-rows per block
}

typedef __attribute__((ext_vector_type(8))) short bf16x8;
typedef __attribute__((ext_vector_type(4))) float f32x4;

__device__ __forceinline__ unsigned short f2bf(float f) {
  unsigned u = __float_as_uint(f);
  return (unsigned short)((u + 0x7fffu + ((u >> 16) & 1u)) >> 16);
}

__device__ __forceinline__ void async_copy16(void* l, const void* g) {
  __builtin_amdgcn_global_load_lds((const __attribute__((address_space(1))) unsigned*)g,
                                   (__attribute__((address_space(3))) unsigned*)l, 16, 0, 0);
}

// ---------------- patchify: images f32 -> patches bf16 [TP][768] ----------------
__global__ void patchify_kernel(const float* __restrict__ img, unsigned short* __restrict__ patches) {
  int idx = blockIdx.x * 256 + threadIdx.x;
  if (idx >= TP * 768) return;
  int t = idx / 768, kf = idx - t * 768;
  int b = t / NPATCH, p = t - b * NPATCH;
  int pi = p / 14, pj = p - pi * 14;
  int c = kf >> 8, rr = (kf >> 4) & 15, cc = kf & 15;
  patches[idx] = f2bf(img[((size_t)(b * 3 + c) * 224 + pi * 16 + rr) * 224 + pj * 16 + cc]);
}

// ---------------- transpose+convert: in f32 [K][N] -> out bf16 [N][K] ----------------
__global__ __launch_bounds__(256) void transpose_kernel(
    const float* __restrict__ in, unsigned short* __restrict__ out,
    int K, int N, long ist, long ost) {
  __shared__ float t[32][33];
  const float* src = in + (size_t)blockIdx.z * ist;
  unsigned short* dst = out + (size_t)blockIdx.z * ost;
  int n0 = blockIdx.x * 32, k0 = blockIdx.y * 32;
  int tx = threadIdx.x & 31, ty = threadIdx.x >> 5;
  #pragma unroll
  for (int i = 0; i < 4; ++i)
    t[ty + i * 8][tx] = src[(size_t)(k0 + ty + i * 8) * N + n0 + tx];
  __syncthreads();
  #pragma unroll
  for (int i = 0; i < 4; ++i)
    dst[(size_t)(n0 + ty + i * 8) * K + k0 + tx] = f2bf(t[tx][ty + i * 8]);
}

// ---------------- MFMA GEMM: C = epi(A @ BT^T + bias) ----------------
// A [Mpad][K] bf16 row-major, BT [N][K] bf16 (pre-transposed). 128x128 tile, BK=32.
enum { EPI_F32 = 0, EPI_GELU_BF16 = 1, EPI_ACC_F32 = 2 };

template<int EPI>
__global__ __launch_bounds__(256) void mfma_gemm_kernel(
    const unsigned short* __restrict__ A, const unsigned short* __restrict__ BT,
    const float* __restrict__ bias, void* __restrict__ C, int M, int N, int K) {
  __shared__ unsigned short As[128 * 32];
  __shared__ unsigned short Bs[128 * 32];
  const int tid = threadIdx.x;
  const int w = tid >> 6, ln = tid & 63;
  const int wr = w >> 1, wc = w & 1;
  const int m0 = blockIdx.y * 128, n0 = blockIdx.x * 128;

  f32x4 acc[4][4] = {};

  const int r0 = tid >> 2, kq = (tid & 3) * 8;  // chunk f = it*256+tid -> row=f>>2, kchunk=f&3
  const unsigned short* Ag = A + (size_t)(m0 + r0) * K + kq;
  const unsigned short* Ag2 = A + (size_t)(m0 + 64 + r0) * K + kq;
  const unsigned short* Bg = BT + (size_t)(n0 + r0) * K + kq;
  const unsigned short* Bg2 = BT + (size_t)(n0 + 64 + r0) * K + kq;
  unsigned short* Al = As + tid * 8;
  unsigned short* Al2 = As + 2048 + tid * 8;
  unsigned short* Bl = Bs + tid * 8;
  unsigned short* Bl2 = Bs + 2048 + tid * 8;

  const int fr = ln & 15, fq = ln >> 4;
  for (int kt = 0; kt < K; kt += 32) {
    async_copy16(Al, Ag + kt);
    async_copy16(Al2, Ag2 + kt);
    async_copy16(Bl, Bg + kt);
    async_copy16(Bl2, Bg2 + kt);
    __syncthreads();
    bf16x8 afr[4], bfr[4];
    #pragma unroll
    for (int i = 0; i < 4; ++i) {
      afr[i] = *(const bf16x8*)(As + (wr * 64 + i * 16 + fr) * 32 + fq * 8);
      bfr[i] = *(const bf16x8*)(Bs + (wc * 64 + i * 16 + fr) * 32 + fq * 8);
    }
    #pragma unroll
    for (int mi = 0; mi < 4; ++mi)
      #pragma unroll
      for (int ni = 0; ni < 4; ++ni)
        acc[mi][ni] = __builtin_amdgcn_mfma_f32_16x16x32_bf16(afr[mi], bfr[ni], acc[mi][ni], 0, 0, 0);
    __syncthreads();
  }

  // C/D layout: col = lane&15, row = (lane>>4)*4 + j  (m89/m91-verified)
  #pragma unroll
  for (int mi = 0; mi < 4; ++mi) {
    #pragma unroll
    for (int j = 0; j < 4; ++j) {
      int row = m0 + wr * 64 + mi * 16 + fq * 4 + j;
      if (row >= M) continue;
      #pragma unroll
      for (int ni = 0; ni < 4; ++ni) {
        int cl = wc * 64 + ni * 16 + fr;
        int col = n0 + cl;
        float vv = acc[mi][ni][j] + bias[n0 + cl];
        if (EPI == EPI_F32) {
          ((float*)C)[(size_t)row * N + col] = vv;
        } else if (EPI == EPI_GELU_BF16) {
          vv = 0.5f * vv * (1.f + erff(vv * 0.70710678118654752f));
          ((unsigned short*)C)[(size_t)row * N + col] = f2bf(vv);
        } else {
          ((float*)C)[(size_t)row * N + col] += vv;
        }
      }
    }
  }
}

// ---------------- pos embed table [S][768] ----------------
__global__ void pos_kernel(float* __restrict__ pe) {
  int idx = blockIdx.x * 256 + threadIdx.x;
  if (idx >= S * D) return;
  int s = idx / D, d = idx - s * D;
  double p = exp((double)d * (-9.210340371976184 / 768.0));
  double ang = (double)s * p;
  pe[idx] = (d & 1) ? (float)cos(ang) : (float)sin(ang);
}

// ---------------- x = concat(cls, tokens) + pos  (f32) ----------------
__global__ void build_x_kernel(const float* __restrict__ tokens, const float* __restrict__ cls,
                               const float* __restrict__ pe, float* __restrict__ x) {
  int idx = blockIdx.x * 256 + threadIdx.x;
  if (idx >= BATCH * S * D) return;
  int d = idx % D;
  int bs = idx / D;
  int s = bs % S;
  int b = bs / S;
  float val = (s == 0) ? cls[d] : tokens[((size_t)b * NPATCH + (s - 1)) * D + d];
  x[idx] = val + pe[s * D + d];
}

// ---------------- LayerNorm f32 in -> bf16 out ----------------
__global__ __launch_bounds__(192) void layernorm_kernel(
    const float* __restrict__ x, const float* __restrict__ g,
    const float* __restrict__ b, unsigned short* __restrict__ out) {
  int t = blockIdx.x;
  int tid = threadIdx.x;
  float4 v = ((const float4*)(x + (size_t)t * D))[tid];
  float s = v.x + v.y + v.z + v.w;
  float s2 = v.x * v.x + v.y * v.y + v.z * v.z + v.w * v.w;
  #pragma unroll
  for (int off = 32; off; off >>= 1) {
    s += __shfl_xor(s, off);
    s2 += __shfl_xor(s2, off);
  }
  __shared__ float rs[3], rs2[3];
  int wid = tid >> 6;
  if ((tid & 63) == 0) { rs[wid] = s; rs2[wid] = s2; }
  __syncthreads();
  float tot = rs[0] + rs[1] + rs[2];
  float tot2 = rs2[0] + rs2[1] + rs2[2];
  float mean = tot * (1.f / D);
  float var = tot2 * (1.f / D) - mean * mean;
  float rstd = rsqrtf(var + 1e-5f);
  float4 gv = ((const float4*)g)[tid];
  float4 bv = ((const float4*)b)[tid];
  float o0 = (v.x - mean) * rstd * gv.x + bv.x;
  float o1 = (v.y - mean) * rstd * gv.y + bv.y;
  float o2 = (v.z - mean) * rstd * gv.z + bv.z;
  float o3 = (v.w - mean) * rstd * gv.w + bv.w;
  unsigned lo = (unsigned)f2bf(o0) | ((unsigned)f2bf(o1) << 16);
  unsigned hi = (unsigned)f2bf(o2) | ((unsigned)f2bf(o3) << 16);
  *(uint2*)(out + (size_t)t * D + tid * 4) = make_uint2(lo, hi);
}

// ---------------- per-head QKV via MFMA: 256 rows x (q,k,v) 64x64 ----------------
__global__ __launch_bounds__(256) void qkv_mfma_kernel(
    const unsigned short* __restrict__ h, const unsigned short* __restrict__ WqT,
    const unsigned short* __restrict__ WkT, const unsigned short* __restrict__ WvT,
    const float* __restrict__ bq, const float* __restrict__ bk, const float* __restrict__ bv,
    unsigned short* __restrict__ q, unsigned short* __restrict__ k2,
    unsigned short* __restrict__ v2) {
  __shared__ unsigned short Hs[256 * 64];  // swizzled: byte ^= ((row&7)<<4)
  int tid = threadIdx.x;
  int w = tid >> 6, ln = tid & 63;
  int t0 = blockIdx.x * 256, hh = blockIdx.y;
  const int fr = ln & 15, fq = ln >> 4;

  #pragma unroll
  for (int it = 0; it < 8; ++it) {
    int f = it * 256 + tid;
    int row = f >> 3, kcs = f & 7;
    int kc = kcs ^ (row & 7);  // pre-swizzled global source, linear LDS dest
    async_copy16(Hs + f * 8, h + (size_t)(t0 + row) * D + hh * 64 + kc * 8);
  }
  __syncthreads();

  bf16x8 afr[4][2];
  #pragma unroll
  for (int mi = 0; mi < 4; ++mi)
    #pragma unroll
    for (int s = 0; s < 2; ++s) {
      int row = w * 64 + mi * 16 + fr;
      int kc = s * 4 + fq;
      afr[mi][s] = *(const bf16x8*)(Hs + row * 64 + (kc ^ (row & 7)) * 8);
    }

  const unsigned short* Ws[3] = {WqT + hh * 4096, WkT + hh * 4096, WvT + hh * 4096};
  const float* Bb[3] = {bq + hh * 64, bk + hh * 64, bv + hh * 64};
  unsigned short* Out[3] = {q, k2, v2};

  #pragma unroll
  for (int p = 0; p < 3; ++p) {
    bf16x8 bfr[4][2];
    #pragma unroll
    for (int ni = 0; ni < 4; ++ni)
      #pragma unroll
      for (int s = 0; s < 2; ++s)
        bfr[ni][s] = *(const bf16x8*)(Ws[p] + (ni * 16 + fr) * 64 + (s * 4 + fq) * 8);
    f32x4 acc[4][4] = {};
    #pragma unroll
    for (int s = 0; s < 2; ++s)
      #pragma unroll
      for (int mi = 0; mi < 4; ++mi)
        #pragma unroll
        for (int ni = 0; ni < 4; ++ni)
          acc[mi][ni] = __builtin_amdgcn_mfma_f32_16x16x32_bf16(afr[mi][s], bfr[ni][s], acc[mi][ni], 0, 0, 0);
    #pragma unroll
    for (int ni = 0; ni < 4; ++ni) {
      float bb = Bb[p][ni * 16 + fr];
      #pragma unroll
      for (int mi = 0; mi < 4; ++mi)
        #pragma unroll
        for (int j = 0; j < 4; ++j) {
          int t = t0 + w * 64 + mi * 16 + fq * 4 + j;
          Out[p][(size_t)t * D + hh * 64 + ni * 16 + fr] = f2bf(acc[mi][ni][j] + bb);
        }
    }
  }
}

// ---------------- attention (f32 compute, bf16 LDS): x += softmax(qk^T/8) v ----------------
// dyn LDS: vs bf16[197*64] | qs bf16[30*64] | ks bf16[197*66] | sc f32[30*197] = 78,700 B
__global__ __launch_bounds__(256) void attn_kernel(
    const unsigned short* __restrict__ q, const unsigned short* __restrict__ k,
    const unsigned short* __restrict__ v, float* __restrict__ x) {
  extern __shared__ char smraw[];
  unsigned short* vs = (unsigned short*)smraw;   // [197][64]
  unsigned short* qs = vs + 197 * 64;            // [30][64]
  unsigned short* ks = qs + QT2 * 64;            // [197][66] (pad 66: conflict-free uint col reads)
  float* sc = (float*)(ks + 197 * 66);           // [30][197]
  int tid = threadIdx.x;
  int b = blockIdx.x, hh = blockIdx.y, qt = blockIdx.z;
  int q0 = qt * QT2;
  int rows = min(QT2, S - q0);

  for (int f = tid; f < 197 * 8; f += 256) {
    int s = f >> 3, e8 = f & 7;
    *(uint4*)(vs + f * 8) = *(const uint4*)(v + (size_t)(b * S + s) * D + hh * 64 + e8 * 8);
  }
  for (int f = tid; f < 197 * 32; f += 256) {
    int s = f >> 5, e2 = f & 31;
    *(unsigned*)(ks + s * 66 + e2 * 2) =
        *(const unsigned*)(k + (size_t)(b * S + s) * D + hh * 64 + e2 * 2);
  }
  for (int f = tid; f < rows * 8; f += 256) {
    int r = f >> 3, e8 = f & 7;
    *(uint4*)(qs + f * 8) = *(const uint4*)(q + (size_t)(b * S + q0 + r) * D + hh * 64 + e8 * 8);
  }
  __syncthreads();

  for (int o = tid; o < rows * S; o += 256) {
    int r = o / S, kj = o - r * S;
    float a = 0.f;
    #pragma unroll
    for (int e2 = 0; e2 < 32; ++e2) {
      unsigned qv = *(const unsigned*)(qs + r * 64 + e2 * 2);
      unsigned kv = *(const unsigned*)(ks + kj * 66 + e2 * 2);
      a += __uint_as_float(qv << 16) * __uint_as_float(kv << 16) +
           __uint_as_float(qv & 0xffff0000u) * __uint_as_float(kv & 0xffff0000u);
    }
    sc[r * S + kj] = a * 0.125f;
  }
  __syncthreads();

  int wid = tid >> 6, lane = tid & 63;
  for (int r = wid; r < rows; r += 4) {
    float vals[4];
    float mx = -1e30f;
    #pragma unroll
    for (int c = 0; c < 4; ++c) {
      int idx = c * 64 + lane;
      vals[c] = (idx < S) ? sc[r * S + idx] : -1e30f;
      mx = fmaxf(mx, vals[c]);
    }
    #pragma unroll
    for (int off = 32; off; off >>= 1) mx = fmaxf(mx, __shfl_xor(mx, off));
    float sum = 0.f;
    #pragma unroll
    for (int c = 0; c < 4; ++c) {
      int idx = c * 64 + lane;
      if (idx < S) { float e = expf(vals[c] - mx); sc[r * S + idx] = e; sum += e; }
    }
    #pragma unroll
    for (int off = 32; off; off >>= 1) sum += __shfl_xor(sum, off);
    float inv = 1.f / sum;
    #pragma unroll
    for (int c = 0; c < 4; ++c) {
      int idx = c * 64 + lane;
      if (idx < S) sc[r * S + idx] *= inv;
    }
  }
  __syncthreads();

  for (int o = tid; o < rows * 32; o += 256) {
    int r = o >> 5, e2 = o & 31;
    float a0 = 0.f, a1 = 0.f;
    #pragma unroll 4
    for (int kj = 0; kj < S; ++kj) {
      float p = sc[r * S + kj];
      unsigned vv = *(const unsigned*)(vs + kj * 64 + e2 * 2);
      a0 += p * __uint_as_float(vv << 16);
      a1 += p * __uint_as_float(vv & 0xffff0000u);
    }
    float* xp = x + (size_t)(b * S + q0 + r) * D + hh * 64 + e2 * 2;
    xp[0] += a0;
    xp[1] += a1;
  }
}

// ---------------- classifier head (f32) ----------------
__global__ __launch_bounds__(256) void head_kernel(
    const float* __restrict__ x, const float* __restrict__ Wo,
    const float* __restrict__ bo, float* __restrict__ out) {
  __shared__ float xs[D];
  int b = blockIdx.x, tid = threadIdx.x;
  for (int i = tid; i < D / 4; i += 256)
    ((float4*)xs)[i] = ((const float4*)(x + (size_t)b * S * D))[i];
  __syncthreads();
  int o = blockIdx.y * 256 + tid;
  if (o < NOUT) {
    float acc = bo[o];
    #pragma unroll 8
    for (int d = 0; d < D; ++d) acc += xs[d] * Wo[(size_t)d * NOUT + o];
    out[(size_t)b * NOUT + o] = acc;
  }
}

extern "C" void kernel_launch(void* const* d_in, const int* in_sizes, int n_in,
                              void* d_out, int out_size, void* d_ws, size_t ws_size,
                              hipStream_t stream) {
  const float* images = (const float*)d_in[0];
  const float* W1 = (const float*)d_in[1];
  const float* b1 = (const float*)d_in[2];
  const float* cls = (const float*)d_in[3];
  const float* ln1_g = (const float*)d_in[4];
  const float* ln1_b = (const float*)d_in[5];
  const float* Wq = (const float*)d_in[6];
  const float* bq = (const float*)d_in[7];
  const float* Wk = (const float*)d_in[8];
  const float* bk = (const float*)d_in[9];
  const float* Wv = (const float*)d_in[10];
  const float* bv = (const float*)d_in[11];
  const float* ln2_g = (const float*)d_in[12];
  const float* ln2_b = (const float*)d_in[13];
  const float* Wm1 = (const float*)d_in[14];
  const float* bm1 = (const float*)d_in[15];
  const float* Wm2 = (const float*)d_in[16];
  const float* bm2 = (const float*)d_in[17];
  const float* Wo = (const float*)d_in[18];
  const float* bo = (const float*)d_in[19];
  float* out = (float*)d_out;

  // ---- ws carve-up (bytes) ----
  char* p = (char*)d_ws;
  float* x = (float*)p;            p += (size_t)T * D * 4;        // 19.37 MB
  unsigned short* h = (unsigned short*)p;   p += (size_t)TPAD * D * 2;
  unsigned short* qb = (unsigned short*)p;  p += (size_t)TPAD * D * 2;
  unsigned short* kb = (unsigned short*)p;  p += (size_t)TPAD * D * 2;
  unsigned short* vb = (unsigned short*)p;  p += (size_t)TPAD * D * 2;
  unsigned short* mlp = (unsigned short*)p; p += (size_t)TPAD * MLPD * 2;
  unsigned short* w1t = (unsigned short*)p; p += (size_t)D * D * 2;
  unsigned short* wqt = (unsigned short*)p; p += (size_t)LYR * NH * 64 * 64 * 2;
  unsigned short* wkt = (unsigned short*)p; p += (size_t)LYR * NH * 64 * 64 * 2;
  unsigned short* wvt = (unsigned short*)p; p += (size_t)LYR * NH * 64 * 64 * 2;
  unsigned short* wm1t = (unsigned short*)p; p += (size_t)MLPD * D * 2;
  unsigned short* wm2t = (unsigned short*)p; p += (size_t)D * MLPD * 2;
  float* pe = (float*)p;           p += (size_t)S * D * 4;
  unsigned short* patches = mlp;            // alias: dead before MLP use
  float* tokens = (float*)qb;               // alias spans qb+kb: dead before QKV use

  const size_t attn_lds = 197 * 64 * 2 + QT2 * 64 * 2 + 197 * 66 * 2 + (size_t)QT2 * S * 4;
  hipFuncSetAttribute((const void*)attn_kernel,
                      hipFuncAttributeMaxDynamicSharedMemorySize, (int)attn_lds);

  // ---- prologue ----
  pos_kernel<<<(S * D + 255) / 256, 256, 0, stream>>>(pe);
  patchify_kernel<<<(TP * 768 + 255) / 256, 256, 0, stream>>>(images, patches);
  transpose_kernel<<<dim3(D / 32, D / 32, 1), 256, 0, stream>>>(W1, w1t, D, D, 0, 0);
  transpose_kernel<<<dim3(2, 2, LYR * NH), 256, 0, stream>>>(Wq, wqt, 64, 64, 4096, 4096);
  transpose_kernel<<<dim3(2, 2, LYR * NH), 256, 0, stream>>>(Wk, wkt, 64, 64, 4096, 4096);
  transpose_kernel<<<dim3(2, 2, LYR * NH), 256, 0, stream>>>(Wv, wvt, 64, 64, 4096, 4096);
  mfma_gemm_kernel<EPI_F32><<<dim3(D / 128, TP / 128), 256, 0, stream>>>(
      patches, w1t, b1, tokens, TP, D, D);
  build_x_kernel<<<(BATCH * S * D + 255) / 256, 256, 0, stream>>>(tokens, cls, pe, x);

  // ---- layers ----
  for (int l = 0; l < LYR; ++l) {
    layernorm_kernel<<<T, 192, 0, stream>>>(x, ln1_g + (size_t)l * D, ln1_b + (size_t)l * D, h);
    qkv_mfma_kernel<<<dim3(TPAD / 256, NH), 256, 0, stream>>>(
        h, wqt + (size_t)l * NH * 4096, wkt + (size_t)l * NH * 4096, wvt + (size_t)l * NH * 4096,
        bq + (size_t)l * NH * 64, bk + (size_t)l * NH * 64, bv + (size_t)l * NH * 64,
        qb, kb, vb);
    attn_kernel<<<dim3(BATCH, NH, (S + QT2 - 1) / QT2), 256, attn_lds, stream>>>(qb, kb, vb, x);
    layernorm_kernel<<<T, 192, 0, stream>>>(x, ln2_g + (size_t)l * D, ln2_b + (size_t)l * D, h);
    transpose_kernel<<<dim3(MLPD / 32, D / 32, 1), 256, 0, stream>>>(
        Wm1 + (size_t)l * D * MLPD, wm1t, D, MLPD, 0, 0);
    mfma_gemm_kernel<EPI_GELU_BF16><<<dim3(MLPD / 128, TPAD / 128), 256, 0, stream>>>(
        h, wm1t, bm1 + (size_t)l * MLPD, mlp, T, MLPD, D);
    transpose_kernel<<<dim3(D / 32, MLPD / 32, 1), 256, 0, stream>>>(
        Wm2 + (size_t)l * MLPD * D, wm2t, MLPD, D, 0, 0);
    mfma_gemm_kernel<EPI_ACC_F32><<<dim3(D / 128, TPAD / 128), 256, 0, stream>>>(
        mlp, wm2t, bm2 + (size_t)l * D, x, T, D, MLPD);
  }

  head_kernel<<<dim3(BATCH, (NOUT + 255) / 256), 256, 0, stream>>>(x, Wo, bo, out);
}